// Round 13
// baseline (1169.212 us; speedup 1.0000x reference)
//
#include <hip/hip_runtime.h>
#include <hip/hip_bf16.h>

typedef _Float16 f16;
typedef _Float16 f16v2 __attribute__((ext_vector_type(2)));
typedef _Float16 f16v4 __attribute__((ext_vector_type(4)));
typedef _Float16 f16v8 __attribute__((ext_vector_type(8)));

#define BB   2
#define LL   21
#define HH   512
#define WW   512
#define RR   20
#define NCH  84            // planes per batch: p(21), Ic*p(63); later b,a
#define HW   (HH*WW)
#define VSEG 64            // rows per strip, fp32 init vbox

// fused-kernel LDS ring geometry (f32 vertical sums, XOR-swizzled; round-4 verified)
#define WROW 576           // padded row: x_s in [0,576): 24 left pad, 512 data, 40 right pad
#define RSTR 2320          // ring-row stride in words: 4*576 + 16 (rotates banks per row)
#define NSTRIP 6
#define NGRP 11            // ceil(max strip rows (86) / 8)

__device__ __forceinline__ float nrminv(int x, int y) {
    int cx = min(x + RR, WW - 1) - max(x - RR, 0) + 1;
    int cy = min(y + RR, HH - 1) - max(y - RR, 0) + 1;
    return 1.0f / (float)(cx * cy);
}

// involution on word indices; consistent for aligned float4 (swz(w+i)=swz(w)+i, i<4, w%4==0)
__device__ __forceinline__ int swz(int w) { return w ^ ((w >> 3) & 0x1C); }

// ---- vertical box fp32 (init only): 4 cols/thread --------------------------
__global__ __launch_bounds__(128) void vboxf_k(const float* __restrict__ src,
                                               float* __restrict__ dst) {
    int pp = blockIdx.y;
    int y0 = blockIdx.x * VSEG;
    const float* s = src + (size_t)pp * HW + threadIdx.x * 4;
    float* d = dst + (size_t)pp * HW + threadIdx.x * 4;
    float s0 = 0.f, s1 = 0.f, s2 = 0.f, s3 = 0.f;
    int lo = y0 - RR; if (lo < 0) lo = 0;
    int hi = y0 + RR;
    for (int yy = lo; yy <= hi; ++yy) {
        float4 v = *(const float4*)(s + (size_t)yy * WW);
        s0 += v.x; s1 += v.y; s2 += v.z; s3 += v.w;
    }
    { float4 o = {s0, s1, s2, s3}; *(float4*)(d + (size_t)y0 * WW) = o; }
    #pragma unroll 4
    for (int y = y0 + 1; y < y0 + VSEG; ++y) {
        int ya = y + RR, ys = y - RR - 1;
        if (ya < HH) {
            float4 v = *(const float4*)(s + (size_t)ya * WW);
            s0 += v.x; s1 += v.y; s2 += v.z; s3 += v.w;
        }
        if (ys >= 0) {
            float4 v = *(const float4*)(s + (size_t)ys * WW);
            s0 -= v.x; s1 -= v.y; s2 -= v.z; s3 -= v.w;
        }
        float4 o = {s0, s1, s2, s3};
        *(float4*)(d + (size_t)y * WW) = o;
    }
}

// ---- horizontal window helpers ---------------------------------------------
template <typename T, typename V4>
__device__ __forceinline__ void load_win16(const T* __restrict__ srow, int x0,
                                           float* __restrict__ raw) {
    #pragma unroll
    for (int c = 0; c < 15; ++c) {
        int st = x0 - 24 + 4 * c;
        if (st >= 0 && st < WW) {
            V4 v = *(const V4*)(srow + st);
            raw[4*c+0] = (float)v.x; raw[4*c+1] = (float)v.y;
            raw[4*c+2] = (float)v.z; raw[4*c+3] = (float)v.w;
        } else {
            raw[4*c+0] = 0.f; raw[4*c+1] = 0.f; raw[4*c+2] = 0.f; raw[4*c+3] = 0.f;
        }
    }
}
__device__ __forceinline__ void slide16(const float* __restrict__ raw,
                                        float* __restrict__ res) {
    float sum = 0.f;
    #pragma unroll
    for (int j = 4; j <= 44; ++j) sum += raw[j];   // [x0-20, x0+20]
    res[0] = sum;
    #pragma unroll
    for (int k = 1; k < 16; ++k) { sum += raw[k+44] - raw[k+3]; res[k] = sum; }
}

// ---- plain horizontal box (init, fp32): 16 px/thread -----------------------
__global__ __launch_bounds__(256) void hboxf_k(const float* __restrict__ src,
                                               float* __restrict__ dst) {
    int pp = blockIdx.y;
    int row = blockIdx.x * 8 + (threadIdx.x >> 5);
    int x0 = (threadIdx.x & 31) << 4;
    const float* srow = src + (size_t)pp * HW + (size_t)row * WW;
    float raw[60], res[16];
    load_win16<float, float4>(srow, x0, raw);
    slide16(raw, res);
    float* drow = dst + (size_t)pp * HW + (size_t)row * WW + x0;
    #pragma unroll
    for (int g = 0; g < 4; ++g) {
        float4 o = {res[4*g], res[4*g+1], res[4*g+2], res[4*g+3]};
        *(float4*)(drow + 4*g) = o;
    }
}

// ---- fused 2D box: producer (vertical running sums -> f32 LDS ring) --------
// BATCHED + UNCONDITIONAL loads: every array element is initialized via a
// row-CLAMPED address (always in-plane), so SROA can promote ra/rb to
// registers. Round-11/12 evidence: conditionally-initialized batch arrays
// went to scratch (localMem) -> +178 MB/dispatch spill writes (rule #20).
// The original guards apply only in the arithmetic phase (numerics identical).
__device__ __forceinline__ void produce8(const f16* __restrict__ pu,
                                         float* __restrict__ ldsrow0,
                                         float* __restrict__ va,
                                         int gy, int yend, int buf,
                                         int ws0, int ws1) {
    f16v8 ra[8], rb[8];
    #pragma unroll
    for (int k = 0; k < 8; ++k) {
        int y = gy + k;
        int ya = y + RR;     if (ya > HH - 1) ya = HH - 1;   // clamp: always valid
        int yb = y - RR - 1; if (yb < 0) yb = 0;             // clamp: always valid
        ra[k] = *(const f16v8*)(pu + (size_t)ya * WW);
        rb[k] = *(const f16v8*)(pu + (size_t)yb * WW);
    }
    #pragma unroll
    for (int k = 0; k < 8; ++k) {
        int y = gy + k;
        if (y < yend) {
            if (y + RR < HH) {
                #pragma unroll
                for (int i = 0; i < 8; ++i) va[i] += (float)ra[k][i];
            }
            if (y - RR - 1 >= 0) {
                #pragma unroll
                for (int i = 0; i < 8; ++i) va[i] -= (float)rb[k][i];
            }
            float* dst = ldsrow0 + (size_t)(buf * 8 + k) * RSTR;
            float4 a = {va[0], va[1], va[2], va[3]};
            float4 b4 = {va[4], va[5], va[6], va[7]};
            *(float4*)(dst + ws0) = a;
            *(float4*)(dst + ws1) = b4;
        }
    }
}

// batched warm-up: rows [lo, hi] into va; loads clamped-unconditional per chunk
__device__ __forceinline__ void warmup(const f16* __restrict__ pu,
                                       float* __restrict__ va, int lo, int hi) {
    for (int y0c = lo; y0c <= hi; y0c += 8) {
        f16v8 r[8];
        #pragma unroll
        for (int k = 0; k < 8; ++k) {
            int yy = y0c + k; if (yy > hi) yy = hi;          // clamp: always valid
            r[k] = *(const f16v8*)(pu + (size_t)yy * WW);
        }
        #pragma unroll
        for (int k = 0; k < 8; ++k)
            if (y0c + k <= hi) {
                #pragma unroll
                for (int i = 0; i < 8; ++i) va[i] += (float)r[k][i];
            }
    }
}

// consumer raw-window load from swizzled LDS ring row
__device__ __forceinline__ void load_raw_lds(const float* __restrict__ base,
                                             int x0, float* __restrict__ raw) {
    #pragma unroll
    for (int k = 0; k < 16; ++k) {
        int w = x0 + 4 * k;
        float4 v = *(const float4*)(base + swz(w));
        raw[4*k+0] = v.x; raw[4*k+1] = v.y; raw[4*k+2] = v.z; raw[4*k+3] = v.w;
    }
}

// zero the pad columns (x_s in [0,24) and [536,576)) of all 16 ring rows x 4 ch
__device__ __forceinline__ void zero_pads(float* __restrict__ lds) {
    for (int p = threadIdx.x; p < 16 * 4 * 64; p += 512) {
        int ringrow = p >> 8;
        int rem = p & 255;
        int chp = rem >> 6, j = rem & 63;
        int w = (j < 24) ? j : (512 + j);
        lds[(size_t)ringrow * RSTR + chp * WROW + swz(w)] = 0.f;
    }
}

// ---- fused: vertical box + horizontal box + 3x3 solve  (U -> V as b,a) -----
__global__ __launch_bounds__(512, 2) void fused_solve_k(const f16* __restrict__ U,
                                                        f16* __restrict__ V,
                                                        const float* __restrict__ Ainv,
                                                        const float* __restrict__ mI) {
    __shared__ float lds[16 * RSTR];     // 145 KB
    int bl = blockIdx.y;
    int b = bl / LL, l = bl - b * LL;
    int strip = blockIdx.x;
    int y0s = (strip * HH) / NSTRIP;
    int yend = ((strip + 1) * HH) / NSTRIP;
    bool prod = (threadIdx.x < 256);

    int pch = threadIdx.x >> 6;          // producer channel 0..3
    int cx = (threadIdx.x & 63) * 8;
    int chsel = (pch == 0) ? l : (LL + (pch - 1) * LL + l);
    const f16* pu = U + (size_t)(b * NCH + chsel) * HW + cx;
    float* ldsrow0 = lds + pch * WROW;
    int ws0 = swz(cx + 24);
    int ws1 = swz(cx + 28);
    float va[8];
    #pragma unroll
    for (int i = 0; i < 8; ++i) va[i] = 0.f;

    zero_pads(lds);

    if (prod) {
        int lo = y0s - RR - 1; if (lo < 0) lo = 0;
        warmup(pu, va, lo, y0s + RR - 1);
        produce8(pu, ldsrow0, va, y0s, yend, 0, ws0, ws1);
    }
    __syncthreads();

    int u = threadIdx.x - 256;
    int r = u >> 5, i = u & 31;          // consumer: row slot, px group
    int x0 = i << 4;

    for (int g = 1; g <= NGRP; ++g) {
        if (prod) {
            if (g < NGRP) produce8(pu, ldsrow0, va, y0s + g * 8, yend, g & 1, ws0, ws1);
        } else {
            int gc = g - 1;
            int row = y0s + gc * 8 + r;
            if (row < yend) {
                float res[4][16];
                const float* rbase = lds + (size_t)((gc & 1) * 8 + r) * RSTR;
                #pragma unroll
                for (int c = 0; c < 4; ++c) {
                    float raw[64];
                    load_raw_lds(rbase + c * WROW, x0, raw);
                    slide16(raw, res[c]);
                }
                size_t pixb = (size_t)row * WW + x0;
                size_t ab = (size_t)b * 6 * HW + pixb;
                size_t mb = (size_t)b * 3 * HW + pixb;
                #pragma unroll
                for (int gq = 0; gq < 4; ++gq) {
                    float iv[6][4], mi[3][4];
                    #pragma unroll
                    for (int j = 0; j < 6; ++j) {
                        float4 v = *(const float4*)(Ainv + ab + (size_t)j * HW + 4 * gq);
                        iv[j][0] = v.x; iv[j][1] = v.y; iv[j][2] = v.z; iv[j][3] = v.w;
                    }
                    #pragma unroll
                    for (int j = 0; j < 3; ++j) {
                        float4 v = *(const float4*)(mI + mb + (size_t)j * HW + 4 * gq);
                        mi[j][0] = v.x; mi[j][1] = v.y; mi[j][2] = v.z; mi[j][3] = v.w;
                    }
                    #pragma unroll
                    for (int e = 0; e < 4; ++e) {
                        int k = 4 * gq + e;
                        float nrm = nrminv(x0 + k, row);
                        float mp   = res[0][k] * nrm;
                        float cov0 = res[1][k] * nrm - mi[0][e] * mp;
                        float cov1 = res[2][k] * nrm - mi[1][e] * mp;
                        float cov2 = res[3][k] * nrm - mi[2][e] * mp;
                        float a0 = iv[0][e] * cov0 + iv[1][e] * cov1 + iv[2][e] * cov2;
                        float a1 = iv[1][e] * cov0 + iv[3][e] * cov1 + iv[4][e] * cov2;
                        float a2 = iv[2][e] * cov0 + iv[4][e] * cov1 + iv[5][e] * cov2;
                        float bb = mp - (a0 * mi[0][e] + a1 * mi[1][e] + a2 * mi[2][e]);
                        res[0][k] = bb; res[1][k] = a0; res[2][k] = a1; res[3][k] = a2;
                    }
                }
                #pragma unroll
                for (int c = 0; c < 4; ++c) {
                    int chx = (c == 0) ? l : (LL + (c - 1) * LL + l);
                    f16* drow = V + (size_t)(b * NCH + chx) * HW + pixb;
                    f16v8 o0, o1;
                    #pragma unroll
                    for (int e = 0; e < 8; ++e) { o0[e] = (f16)res[c][e]; o1[e] = (f16)res[c][8+e]; }
                    *(f16v8*)(drow) = o0;
                    *(f16v8*)(drow + 8) = o1;
                }
            }
        }
        if (g < NGRP) __syncthreads();
    }
}

// ---- fused: vertical box + horizontal box + q combine  (V -> q planes) -----
__global__ __launch_bounds__(512, 2) void fused_q_k(const f16* __restrict__ V,
                                                    const float* __restrict__ Refs,
                                                    f16* __restrict__ Q) {
    __shared__ float lds[16 * RSTR];
    int bl = blockIdx.y;
    int b = bl / LL, l = bl - b * LL;
    int strip = blockIdx.x;
    int y0s = (strip * HH) / NSTRIP;
    int yend = ((strip + 1) * HH) / NSTRIP;
    bool prod = (threadIdx.x < 256);

    int pch = threadIdx.x >> 6;
    int cx = (threadIdx.x & 63) * 8;
    int chsel = (pch == 0) ? l : (LL + (pch - 1) * LL + l);
    const f16* pu = V + (size_t)(b * NCH + chsel) * HW + cx;
    float* ldsrow0 = lds + pch * WROW;
    int ws0 = swz(cx + 24);
    int ws1 = swz(cx + 28);
    float va[8];
    #pragma unroll
    for (int i = 0; i < 8; ++i) va[i] = 0.f;

    zero_pads(lds);

    if (prod) {
        int lo = y0s - RR - 1; if (lo < 0) lo = 0;
        warmup(pu, va, lo, y0s + RR - 1);
        produce8(pu, ldsrow0, va, y0s, yend, 0, ws0, ws1);
    }
    __syncthreads();

    int u = threadIdx.x - 256;
    int r = u >> 5, i = u & 31;
    int x0 = i << 4;

    for (int g = 1; g <= NGRP; ++g) {
        if (prod) {
            if (g < NGRP) produce8(pu, ldsrow0, va, y0s + g * 8, yend, g & 1, ws0, ws1);
        } else {
            int gc = g - 1;
            int row = y0s + gc * 8 + r;
            if (row < yend) {
                float res[4][16];
                const float* rbase = lds + (size_t)((gc & 1) * 8 + r) * RSTR;
                #pragma unroll
                for (int c = 0; c < 4; ++c) {
                    float raw[64];
                    load_raw_lds(rbase + c * WROW, x0, raw);
                    slide16(raw, res[c]);
                }
                size_t pixb = (size_t)row * WW + x0;
                f16* qrow = Q + (size_t)(b * LL + l) * HW + pixb;
                f16 tmpo[16];
                #pragma unroll
                for (int gq = 0; gq < 4; ++gq) {
                    float4 i0 = *(const float4*)(Refs + ((size_t)b * 3 + 0) * HW + pixb + 4 * gq);
                    float4 i1 = *(const float4*)(Refs + ((size_t)b * 3 + 1) * HW + pixb + 4 * gq);
                    float4 i2 = *(const float4*)(Refs + ((size_t)b * 3 + 2) * HW + pixb + 4 * gq);
                    float ic0[4] = {i0.x, i0.y, i0.z, i0.w};
                    float ic1[4] = {i1.x, i1.y, i1.z, i1.w};
                    float ic2[4] = {i2.x, i2.y, i2.z, i2.w};
                    #pragma unroll
                    for (int e = 0; e < 4; ++e) {
                        int k = 4 * gq + e;
                        float nrm = nrminv(x0 + k, row);
                        float q = (res[0][k] + res[1][k] * ic0[e] + res[2][k] * ic1[e]
                                   + res[3][k] * ic2[e]) * nrm;
                        tmpo[k] = (f16)q;
                    }
                }
                f16v8 o0, o1;
                #pragma unroll
                for (int e = 0; e < 8; ++e) { o0[e] = tmpo[e]; o1[e] = tmpo[8+e]; }
                *(f16v8*)(qrow) = o0;
                *(f16v8*)(qrow + 8) = o1;
            }
        }
        if (g < NGRP) __syncthreads();
    }
}

// ---- products: I and I*I into 9-plane/b fp32 compact buffer ----------------
__global__ __launch_bounds__(256) void prod_k(float* __restrict__ Pf,
                                              const float* __restrict__ Refs) {
    int idx = blockIdx.x * 256 + threadIdx.x;
    int b = idx >> 18, pix = idx & (HW - 1);
    float I0 = Refs[((size_t)b * 3 + 0) * HW + pix];
    float I1 = Refs[((size_t)b * 3 + 1) * HW + pix];
    float I2 = Refs[((size_t)b * 3 + 2) * HW + pix];
    size_t base = (size_t)b * 9 * HW + pix;
    Pf[base + (size_t)0 * HW] = I0;
    Pf[base + (size_t)1 * HW] = I1;
    Pf[base + (size_t)2 * HW] = I2;
    Pf[base + (size_t)3 * HW] = I0 * I0;
    Pf[base + (size_t)4 * HW] = I0 * I1;
    Pf[base + (size_t)5 * HW] = I0 * I2;
    Pf[base + (size_t)6 * HW] = I1 * I1;
    Pf[base + (size_t)7 * HW] = I1 * I2;
    Pf[base + (size_t)8 * HW] = I2 * I2;
}

// ---- prep: boxed(I,II) fp32 -> Ainv (6 planes), mI (3 planes) --------------
__global__ __launch_bounds__(256) void prep_k(const float* __restrict__ Bf,
                                              float* __restrict__ Ainv, float* __restrict__ mI,
                                              const float* __restrict__ epsp) {
    int idx = blockIdx.x * 256 + threadIdx.x;
    int b = idx >> 18, pix = idx & (HW - 1);
    int x = pix & (WW - 1), y = pix >> 9;
    float nrm = nrminv(x, y);
    float eps = epsp[0];
    size_t base = (size_t)b * 9 * HW + pix;
    float m0 = Bf[base + (size_t)0 * HW] * nrm;
    float m1 = Bf[base + (size_t)1 * HW] * nrm;
    float m2 = Bf[base + (size_t)2 * HW] * nrm;
    float v00 = Bf[base + (size_t)3 * HW] * nrm - m0 * m0 + eps;
    float v01 = Bf[base + (size_t)4 * HW] * nrm - m0 * m1;
    float v02 = Bf[base + (size_t)5 * HW] * nrm - m0 * m2;
    float v11 = Bf[base + (size_t)6 * HW] * nrm - m1 * m1 + eps;
    float v12 = Bf[base + (size_t)7 * HW] * nrm - m1 * m2;
    float v22 = Bf[base + (size_t)8 * HW] * nrm - m2 * m2 + eps;
    float c00 = v11 * v22 - v12 * v12;
    float c01 = v02 * v12 - v01 * v22;
    float c02 = v01 * v12 - v02 * v11;
    float c11 = v00 * v22 - v02 * v02;
    float c12 = v01 * v02 - v00 * v12;
    float c22 = v00 * v11 - v01 * v01;
    float det = v00 * c00 + v01 * c01 + v02 * c02;
    float id = 1.0f / det;
    size_t ab = (size_t)b * 6 * HW + pix;
    Ainv[ab + (size_t)0 * HW] = c00 * id;
    Ainv[ab + (size_t)1 * HW] = c01 * id;
    Ainv[ab + (size_t)2 * HW] = c02 * id;
    Ainv[ab + (size_t)3 * HW] = c11 * id;
    Ainv[ab + (size_t)4 * HW] = c12 * id;
    Ainv[ab + (size_t)5 * HW] = c22 * id;
    size_t mb = (size_t)b * 3 * HW + pix;
    mI[mb]                  = m0;
    mI[mb + (size_t)HW]     = m1;
    mI[mb + (size_t)2 * HW] = m2;
}

// ---- fused: E=E0+q, Q=softmax(-E), p=W.Q, Ip (2 px/thread) -----------------
// mode 0: Q0 from E0 only; 1: mid; 2: last (fp32 Q -> out)
__global__ __launch_bounds__(256) void e_k(const f16* __restrict__ Q,
                                           f16* __restrict__ pout,
                                           const float* __restrict__ E0,
                                           const float* __restrict__ Refs,
                                           const float* __restrict__ Wf,
                                           float* __restrict__ out, int mode) {
    int idx = blockIdx.x * 256 + threadIdx.x;
    int b = idx >> 17;
    int pix = (idx & (HW / 2 - 1)) * 2;
    size_t base  = (size_t)b * NCH * HW + pix;
    size_t ebase = (size_t)b * LL * HW + pix;
    float2 Ic0 = *(const float2*)(Refs + ((size_t)b * 3 + 0) * HW + pix);
    float2 Ic1 = *(const float2*)(Refs + ((size_t)b * 3 + 1) * HW + pix);
    float2 Ic2 = *(const float2*)(Refs + ((size_t)b * 3 + 2) * HW + pix);
    float Ev0[LL], Ev1[LL];
    float m0 = -1e30f, m1 = -1e30f;
    #pragma unroll
    for (int l = 0; l < LL; ++l) {
        float2 e0 = *(const float2*)(E0 + ebase + (size_t)l * HW);
        float v0 = e0.x, v1 = e0.y;
        if (mode != 0) {
            f16v2 qv = *(const f16v2*)(Q + ebase + (size_t)l * HW);
            v0 += (float)qv.x; v1 += (float)qv.y;
        }
        Ev0[l] = -v0; Ev1[l] = -v1;
        m0 = fmaxf(m0, Ev0[l]); m1 = fmaxf(m1, Ev1[l]);
    }
    float s0 = 0.f, s1 = 0.f;
    #pragma unroll
    for (int l = 0; l < LL; ++l) {
        Ev0[l] = __expf(Ev0[l] - m0); s0 += Ev0[l];
        Ev1[l] = __expf(Ev1[l] - m1); s1 += Ev1[l];
    }
    float i0 = 1.0f / s0, i1 = 1.0f / s1;
    if (mode == 2) {
        #pragma unroll
        for (int l = 0; l < LL; ++l) {
            float2 o; o.x = Ev0[l] * i0; o.y = Ev1[l] * i1;
            *(float2*)(out + ebase + (size_t)l * HW) = o;
        }
    } else {
        #pragma unroll
        for (int l = 0; l < LL; ++l) { Ev0[l] *= i0; Ev1[l] *= i1; }
        #pragma unroll
        for (int l = 0; l < LL; ++l) {
            float p0 = 0.f, p1 = 0.f;
            #pragma unroll
            for (int m = 0; m < LL; ++m) {
                float w = Wf[l * LL + m];
                p0 += w * Ev0[m]; p1 += w * Ev1[m];
            }
            f16v2 o;
            o.x = (f16)p0; o.y = (f16)p1;
            *(f16v2*)(pout + base + (size_t)l * HW) = o;
            o.x = (f16)(p0 * Ic0.x); o.y = (f16)(p1 * Ic0.y);
            *(f16v2*)(pout + base + (size_t)(LL + 0*LL + l) * HW) = o;
            o.x = (f16)(p0 * Ic1.x); o.y = (f16)(p1 * Ic1.y);
            *(f16v2*)(pout + base + (size_t)(LL + 1*LL + l) * HW) = o;
            o.x = (f16)(p0 * Ic2.x); o.y = (f16)(p1 * Ic2.y);
            *(f16v2*)(pout + base + (size_t)(LL + 2*LL + l) * HW) = o;
        }
    }
}

// ---- host ------------------------------------------------------------------
extern "C" void kernel_launch(void* const* d_in, const int* in_sizes, int n_in,
                              void* d_out, int out_size, void* d_ws, size_t ws_size,
                              hipStream_t stream) {
    const float* E0   = (const float*)d_in[0];
    const float* Refs = (const float*)d_in[1];
    const float* Wmu  = (const float*)d_in[2];
    const float* epsp = (const float*)d_in[3];
    float* out = (float*)d_out;

    size_t Ub = (size_t)BB * NCH * HW * 2;   // 84 MB fp16
    size_t Ab = (size_t)BB * 6 * HW * 4;     // 12 MB fp32
    size_t Mb = (size_t)BB * 3 * HW * 4;     // 6 MB fp32
    char* ws = (char*)d_ws;
    f16*   U    = (f16*)ws;
    f16*   V    = (f16*)(ws + Ub);           // loop: holds b,a planes (solve out)
    float* Ainv = (float*)(ws + 2 * Ub);
    float* mI   = (float*)(ws + 2 * Ub + Ab);
    f16*   Qb   = (f16*)(ws + 2 * Ub + Ab + Mb);  // 21 fp16 q planes x BB
    float* Uf   = (float*)U;                 // init fp32 alias (9 planes/b)
    float* Vf   = (float*)V;

    int nblk = (BB * HW) / 256;
    // init: I, I*I -> 2D box (fp32) -> Ainv, mI
    prod_k<<<nblk, 256, 0, stream>>>(Uf, Refs);
    vboxf_k<<<dim3(HH / VSEG, BB * 9), 128, 0, stream>>>(Uf, Vf);
    hboxf_k<<<dim3(HH / 8, BB * 9), 256, 0, stream>>>(Vf, Uf);
    prep_k<<<nblk, 256, 0, stream>>>(Uf, Ainv, mI, epsp);
    // Q0 -> p, Ip into U (mode 0 reads no Q)
    e_k<<<(BB * HW / 2) / 256, 256, 0, stream>>>(Qb, U, E0, Refs, Wmu, out, 0);

    for (int t = 1; t <= 5; ++t) {
        fused_solve_k<<<dim3(NSTRIP, BB * LL), 512, 0, stream>>>(U, V, Ainv, mI);
        fused_q_k<<<dim3(NSTRIP, BB * LL), 512, 0, stream>>>(V, Refs, Qb);
        e_k<<<(BB * HW / 2) / 256, 256, 0, stream>>>(Qb, U, E0, Refs, Wmu, out,
                                                     t == 5 ? 2 : 1);
    }
}

// Round 14
// 1165.773 us; speedup vs baseline: 1.0030x; 1.0030x over previous
//
#include <hip/hip_runtime.h>
#include <hip/hip_bf16.h>

typedef _Float16 f16;
typedef _Float16 f16v2 __attribute__((ext_vector_type(2)));
typedef _Float16 f16v4 __attribute__((ext_vector_type(4)));
typedef _Float16 f16v8 __attribute__((ext_vector_type(8)));

#define BB   2
#define LL   21
#define HH   512
#define WW   512
#define RR   20
#define NCH  84            // planes per batch: p(21), Ic*p(63); later b,a
#define HW   (HH*WW)
#define VSEG 64            // rows per strip, fp32 init vbox

// fused-kernel LDS ring geometry (f32 vertical sums, XOR-swizzled; round-4 verified)
#define WROW 576           // padded row: x_s in [0,576): 24 left pad, 512 data, 40 right pad
#define RSTR 2320          // ring-row stride in words: 4*576 + 16 (rotates banks per row)
#define NSTRIP 6
#define NGRP 11            // ceil(max strip rows (86) / 8)

__device__ __forceinline__ float nrminv(int x, int y) {
    int cx = min(x + RR, WW - 1) - max(x - RR, 0) + 1;
    int cy = min(y + RR, HH - 1) - max(y - RR, 0) + 1;
    return 1.0f / (float)(cx * cy);
}

// involution on word indices; consistent for aligned float4 (swz(w+i)=swz(w)+i, i<4, w%4==0)
__device__ __forceinline__ int swz(int w) { return w ^ ((w >> 3) & 0x1C); }

// ---- vertical box fp32 (init only): 4 cols/thread --------------------------
__global__ __launch_bounds__(128) void vboxf_k(const float* __restrict__ src,
                                               float* __restrict__ dst) {
    int pp = blockIdx.y;
    int y0 = blockIdx.x * VSEG;
    const float* s = src + (size_t)pp * HW + threadIdx.x * 4;
    float* d = dst + (size_t)pp * HW + threadIdx.x * 4;
    float s0 = 0.f, s1 = 0.f, s2 = 0.f, s3 = 0.f;
    int lo = y0 - RR; if (lo < 0) lo = 0;
    int hi = y0 + RR;
    for (int yy = lo; yy <= hi; ++yy) {
        float4 v = *(const float4*)(s + (size_t)yy * WW);
        s0 += v.x; s1 += v.y; s2 += v.z; s3 += v.w;
    }
    { float4 o = {s0, s1, s2, s3}; *(float4*)(d + (size_t)y0 * WW) = o; }
    #pragma unroll 4
    for (int y = y0 + 1; y < y0 + VSEG; ++y) {
        int ya = y + RR, ys = y - RR - 1;
        if (ya < HH) {
            float4 v = *(const float4*)(s + (size_t)ya * WW);
            s0 += v.x; s1 += v.y; s2 += v.z; s3 += v.w;
        }
        if (ys >= 0) {
            float4 v = *(const float4*)(s + (size_t)ys * WW);
            s0 -= v.x; s1 -= v.y; s2 -= v.z; s3 -= v.w;
        }
        float4 o = {s0, s1, s2, s3};
        *(float4*)(d + (size_t)y * WW) = o;
    }
}

// ---- horizontal window helpers ---------------------------------------------
template <typename T, typename V4>
__device__ __forceinline__ void load_win16(const T* __restrict__ srow, int x0,
                                           float* __restrict__ raw) {
    #pragma unroll
    for (int c = 0; c < 15; ++c) {
        int st = x0 - 24 + 4 * c;
        if (st >= 0 && st < WW) {
            V4 v = *(const V4*)(srow + st);
            raw[4*c+0] = (float)v.x; raw[4*c+1] = (float)v.y;
            raw[4*c+2] = (float)v.z; raw[4*c+3] = (float)v.w;
        } else {
            raw[4*c+0] = 0.f; raw[4*c+1] = 0.f; raw[4*c+2] = 0.f; raw[4*c+3] = 0.f;
        }
    }
}
__device__ __forceinline__ void slide16(const float* __restrict__ raw,
                                        float* __restrict__ res) {
    float sum = 0.f;
    #pragma unroll
    for (int j = 4; j <= 44; ++j) sum += raw[j];   // [x0-20, x0+20]
    res[0] = sum;
    #pragma unroll
    for (int k = 1; k < 16; ++k) { sum += raw[k+44] - raw[k+3]; res[k] = sum; }
}

// ---- plain horizontal box (init, fp32): 16 px/thread -----------------------
__global__ __launch_bounds__(256) void hboxf_k(const float* __restrict__ src,
                                               float* __restrict__ dst) {
    int pp = blockIdx.y;
    int row = blockIdx.x * 8 + (threadIdx.x >> 5);
    int x0 = (threadIdx.x & 31) << 4;
    const float* srow = src + (size_t)pp * HW + (size_t)row * WW;
    float raw[60], res[16];
    load_win16<float, float4>(srow, x0, raw);
    slide16(raw, res);
    float* drow = dst + (size_t)pp * HW + (size_t)row * WW + x0;
    #pragma unroll
    for (int g = 0; g < 4; ++g) {
        float4 o = {res[4*g], res[4*g+1], res[4*g+2], res[4*g+3]};
        *(float4*)(drow + 4*g) = o;
    }
}

// ---- fused 2D box: producer (vertical running sums -> f32 LDS ring) --------
// BATCHED via 16 NAMED f16v8 scalars (not arrays). Rounds 11-13: array batches
// (ra[8]/rb[8]) land in scratch regardless of init style -> +178 MB/dispatch
// spill writes. Named locals are SSA values; no aggregate for SROA to punt on.
__device__ __forceinline__ const f16v8* rowclamp(const f16* __restrict__ pu, int y) {
    int yc = y < 0 ? 0 : (y > HH - 1 ? HH - 1 : y);
    return (const f16v8*)(pu + (size_t)yc * WW);
}

__device__ __forceinline__ void pstep(const f16v8& ra, const f16v8& rb,
                                      int y, int yend, int k,
                                      float* __restrict__ va,
                                      float* __restrict__ ldsrow0,
                                      int buf, int ws0, int ws1) {
    if (y < yend) {
        if (y + RR < HH) {
            #pragma unroll
            for (int i = 0; i < 8; ++i) va[i] += (float)ra[i];
        }
        if (y - RR - 1 >= 0) {
            #pragma unroll
            for (int i = 0; i < 8; ++i) va[i] -= (float)rb[i];
        }
        float* dst = ldsrow0 + (size_t)(buf * 8 + k) * RSTR;
        float4 a = {va[0], va[1], va[2], va[3]};
        float4 b4 = {va[4], va[5], va[6], va[7]};
        *(float4*)(dst + ws0) = a;
        *(float4*)(dst + ws1) = b4;
    }
}

__device__ __forceinline__ void produce8(const f16* __restrict__ pu,
                                         float* __restrict__ ldsrow0,
                                         float* __restrict__ va,
                                         int gy, int yend, int buf,
                                         int ws0, int ws1) {
    f16v8 a0 = *rowclamp(pu, gy + 0 + RR), b0 = *rowclamp(pu, gy + 0 - RR - 1);
    f16v8 a1 = *rowclamp(pu, gy + 1 + RR), b1 = *rowclamp(pu, gy + 1 - RR - 1);
    f16v8 a2 = *rowclamp(pu, gy + 2 + RR), b2 = *rowclamp(pu, gy + 2 - RR - 1);
    f16v8 a3 = *rowclamp(pu, gy + 3 + RR), b3 = *rowclamp(pu, gy + 3 - RR - 1);
    f16v8 a4 = *rowclamp(pu, gy + 4 + RR), b4 = *rowclamp(pu, gy + 4 - RR - 1);
    f16v8 a5 = *rowclamp(pu, gy + 5 + RR), b5 = *rowclamp(pu, gy + 5 - RR - 1);
    f16v8 a6 = *rowclamp(pu, gy + 6 + RR), b6 = *rowclamp(pu, gy + 6 - RR - 1);
    f16v8 a7 = *rowclamp(pu, gy + 7 + RR), b7 = *rowclamp(pu, gy + 7 - RR - 1);
    pstep(a0, b0, gy + 0, yend, 0, va, ldsrow0, buf, ws0, ws1);
    pstep(a1, b1, gy + 1, yend, 1, va, ldsrow0, buf, ws0, ws1);
    pstep(a2, b2, gy + 2, yend, 2, va, ldsrow0, buf, ws0, ws1);
    pstep(a3, b3, gy + 3, yend, 3, va, ldsrow0, buf, ws0, ws1);
    pstep(a4, b4, gy + 4, yend, 4, va, ldsrow0, buf, ws0, ws1);
    pstep(a5, b5, gy + 5, yend, 5, va, ldsrow0, buf, ws0, ws1);
    pstep(a6, b6, gy + 6, yend, 6, va, ldsrow0, buf, ws0, ws1);
    pstep(a7, b7, gy + 7, yend, 7, va, ldsrow0, buf, ws0, ws1);
}

__device__ __forceinline__ const f16v8* rowhi(const f16* __restrict__ pu, int y, int hi) {
    int yc = y > hi ? hi : y;
    return (const f16v8*)(pu + (size_t)yc * WW);
}
__device__ __forceinline__ void wadd(const f16v8& r, bool valid,
                                     float* __restrict__ va) {
    if (valid) {
        #pragma unroll
        for (int i = 0; i < 8; ++i) va[i] += (float)r[i];
    }
}
// batched warm-up: rows [lo, hi] into va; 8 named scalar loads per chunk
__device__ __forceinline__ void warmup(const f16* __restrict__ pu,
                                       float* __restrict__ va, int lo, int hi) {
    for (int y0c = lo; y0c <= hi; y0c += 8) {
        f16v8 r0 = *rowhi(pu, y0c + 0, hi);
        f16v8 r1 = *rowhi(pu, y0c + 1, hi);
        f16v8 r2 = *rowhi(pu, y0c + 2, hi);
        f16v8 r3 = *rowhi(pu, y0c + 3, hi);
        f16v8 r4 = *rowhi(pu, y0c + 4, hi);
        f16v8 r5 = *rowhi(pu, y0c + 5, hi);
        f16v8 r6 = *rowhi(pu, y0c + 6, hi);
        f16v8 r7 = *rowhi(pu, y0c + 7, hi);
        wadd(r0, true, va);
        wadd(r1, y0c + 1 <= hi, va);
        wadd(r2, y0c + 2 <= hi, va);
        wadd(r3, y0c + 3 <= hi, va);
        wadd(r4, y0c + 4 <= hi, va);
        wadd(r5, y0c + 5 <= hi, va);
        wadd(r6, y0c + 6 <= hi, va);
        wadd(r7, y0c + 7 <= hi, va);
    }
}

// consumer raw-window load from swizzled LDS ring row
__device__ __forceinline__ void load_raw_lds(const float* __restrict__ base,
                                             int x0, float* __restrict__ raw) {
    #pragma unroll
    for (int k = 0; k < 16; ++k) {
        int w = x0 + 4 * k;
        float4 v = *(const float4*)(base + swz(w));
        raw[4*k+0] = v.x; raw[4*k+1] = v.y; raw[4*k+2] = v.z; raw[4*k+3] = v.w;
    }
}

// zero the pad columns (x_s in [0,24) and [536,576)) of all 16 ring rows x 4 ch
__device__ __forceinline__ void zero_pads(float* __restrict__ lds) {
    for (int p = threadIdx.x; p < 16 * 4 * 64; p += 512) {
        int ringrow = p >> 8;
        int rem = p & 255;
        int chp = rem >> 6, j = rem & 63;
        int w = (j < 24) ? j : (512 + j);
        lds[(size_t)ringrow * RSTR + chp * WROW + swz(w)] = 0.f;
    }
}

// ---- fused: vertical box + horizontal box + 3x3 solve  (U -> V as b,a) -----
__global__ __launch_bounds__(512, 2) void fused_solve_k(const f16* __restrict__ U,
                                                        f16* __restrict__ V,
                                                        const float* __restrict__ Ainv,
                                                        const float* __restrict__ mI) {
    __shared__ float lds[16 * RSTR];     // 145 KB
    int bl = blockIdx.y;
    int b = bl / LL, l = bl - b * LL;
    int strip = blockIdx.x;
    int y0s = (strip * HH) / NSTRIP;
    int yend = ((strip + 1) * HH) / NSTRIP;
    bool prod = (threadIdx.x < 256);

    int pch = threadIdx.x >> 6;          // producer channel 0..3
    int cx = (threadIdx.x & 63) * 8;
    int chsel = (pch == 0) ? l : (LL + (pch - 1) * LL + l);
    const f16* pu = U + (size_t)(b * NCH + chsel) * HW + cx;
    float* ldsrow0 = lds + pch * WROW;
    int ws0 = swz(cx + 24);
    int ws1 = swz(cx + 28);
    float va[8];
    #pragma unroll
    for (int i = 0; i < 8; ++i) va[i] = 0.f;

    zero_pads(lds);

    if (prod) {
        int lo = y0s - RR - 1; if (lo < 0) lo = 0;
        warmup(pu, va, lo, y0s + RR - 1);
        produce8(pu, ldsrow0, va, y0s, yend, 0, ws0, ws1);
    }
    __syncthreads();

    int u = threadIdx.x - 256;
    int r = u >> 5, i = u & 31;          // consumer: row slot, px group
    int x0 = i << 4;

    for (int g = 1; g <= NGRP; ++g) {
        if (prod) {
            if (g < NGRP) produce8(pu, ldsrow0, va, y0s + g * 8, yend, g & 1, ws0, ws1);
        } else {
            int gc = g - 1;
            int row = y0s + gc * 8 + r;
            if (row < yend) {
                float res[4][16];
                const float* rbase = lds + (size_t)((gc & 1) * 8 + r) * RSTR;
                #pragma unroll
                for (int c = 0; c < 4; ++c) {
                    float raw[64];
                    load_raw_lds(rbase + c * WROW, x0, raw);
                    slide16(raw, res[c]);
                }
                size_t pixb = (size_t)row * WW + x0;
                size_t ab = (size_t)b * 6 * HW + pixb;
                size_t mb = (size_t)b * 3 * HW + pixb;
                #pragma unroll
                for (int gq = 0; gq < 4; ++gq) {
                    float iv[6][4], mi[3][4];
                    #pragma unroll
                    for (int j = 0; j < 6; ++j) {
                        float4 v = *(const float4*)(Ainv + ab + (size_t)j * HW + 4 * gq);
                        iv[j][0] = v.x; iv[j][1] = v.y; iv[j][2] = v.z; iv[j][3] = v.w;
                    }
                    #pragma unroll
                    for (int j = 0; j < 3; ++j) {
                        float4 v = *(const float4*)(mI + mb + (size_t)j * HW + 4 * gq);
                        mi[j][0] = v.x; mi[j][1] = v.y; mi[j][2] = v.z; mi[j][3] = v.w;
                    }
                    #pragma unroll
                    for (int e = 0; e < 4; ++e) {
                        int k = 4 * gq + e;
                        float nrm = nrminv(x0 + k, row);
                        float mp   = res[0][k] * nrm;
                        float cov0 = res[1][k] * nrm - mi[0][e] * mp;
                        float cov1 = res[2][k] * nrm - mi[1][e] * mp;
                        float cov2 = res[3][k] * nrm - mi[2][e] * mp;
                        float a0 = iv[0][e] * cov0 + iv[1][e] * cov1 + iv[2][e] * cov2;
                        float a1 = iv[1][e] * cov0 + iv[3][e] * cov1 + iv[4][e] * cov2;
                        float a2 = iv[2][e] * cov0 + iv[4][e] * cov1 + iv[5][e] * cov2;
                        float bb = mp - (a0 * mi[0][e] + a1 * mi[1][e] + a2 * mi[2][e]);
                        res[0][k] = bb; res[1][k] = a0; res[2][k] = a1; res[3][k] = a2;
                    }
                }
                #pragma unroll
                for (int c = 0; c < 4; ++c) {
                    int chx = (c == 0) ? l : (LL + (c - 1) * LL + l);
                    f16* drow = V + (size_t)(b * NCH + chx) * HW + pixb;
                    f16v8 o0, o1;
                    #pragma unroll
                    for (int e = 0; e < 8; ++e) { o0[e] = (f16)res[c][e]; o1[e] = (f16)res[c][8+e]; }
                    *(f16v8*)(drow) = o0;
                    *(f16v8*)(drow + 8) = o1;
                }
            }
        }
        if (g < NGRP) __syncthreads();
    }
}

// ---- fused: vertical box + horizontal box + q combine  (V -> q planes) -----
__global__ __launch_bounds__(512, 2) void fused_q_k(const f16* __restrict__ V,
                                                    const float* __restrict__ Refs,
                                                    f16* __restrict__ Q) {
    __shared__ float lds[16 * RSTR];
    int bl = blockIdx.y;
    int b = bl / LL, l = bl - b * LL;
    int strip = blockIdx.x;
    int y0s = (strip * HH) / NSTRIP;
    int yend = ((strip + 1) * HH) / NSTRIP;
    bool prod = (threadIdx.x < 256);

    int pch = threadIdx.x >> 6;
    int cx = (threadIdx.x & 63) * 8;
    int chsel = (pch == 0) ? l : (LL + (pch - 1) * LL + l);
    const f16* pu = V + (size_t)(b * NCH + chsel) * HW + cx;
    float* ldsrow0 = lds + pch * WROW;
    int ws0 = swz(cx + 24);
    int ws1 = swz(cx + 28);
    float va[8];
    #pragma unroll
    for (int i = 0; i < 8; ++i) va[i] = 0.f;

    zero_pads(lds);

    if (prod) {
        int lo = y0s - RR - 1; if (lo < 0) lo = 0;
        warmup(pu, va, lo, y0s + RR - 1);
        produce8(pu, ldsrow0, va, y0s, yend, 0, ws0, ws1);
    }
    __syncthreads();

    int u = threadIdx.x - 256;
    int r = u >> 5, i = u & 31;
    int x0 = i << 4;

    for (int g = 1; g <= NGRP; ++g) {
        if (prod) {
            if (g < NGRP) produce8(pu, ldsrow0, va, y0s + g * 8, yend, g & 1, ws0, ws1);
        } else {
            int gc = g - 1;
            int row = y0s + gc * 8 + r;
            if (row < yend) {
                float res[4][16];
                const float* rbase = lds + (size_t)((gc & 1) * 8 + r) * RSTR;
                #pragma unroll
                for (int c = 0; c < 4; ++c) {
                    float raw[64];
                    load_raw_lds(rbase + c * WROW, x0, raw);
                    slide16(raw, res[c]);
                }
                size_t pixb = (size_t)row * WW + x0;
                f16* qrow = Q + (size_t)(b * LL + l) * HW + pixb;
                f16 tmpo[16];
                #pragma unroll
                for (int gq = 0; gq < 4; ++gq) {
                    float4 i0 = *(const float4*)(Refs + ((size_t)b * 3 + 0) * HW + pixb + 4 * gq);
                    float4 i1 = *(const float4*)(Refs + ((size_t)b * 3 + 1) * HW + pixb + 4 * gq);
                    float4 i2 = *(const float4*)(Refs + ((size_t)b * 3 + 2) * HW + pixb + 4 * gq);
                    float ic0[4] = {i0.x, i0.y, i0.z, i0.w};
                    float ic1[4] = {i1.x, i1.y, i1.z, i1.w};
                    float ic2[4] = {i2.x, i2.y, i2.z, i2.w};
                    #pragma unroll
                    for (int e = 0; e < 4; ++e) {
                        int k = 4 * gq + e;
                        float nrm = nrminv(x0 + k, row);
                        float q = (res[0][k] + res[1][k] * ic0[e] + res[2][k] * ic1[e]
                                   + res[3][k] * ic2[e]) * nrm;
                        tmpo[k] = (f16)q;
                    }
                }
                f16v8 o0, o1;
                #pragma unroll
                for (int e = 0; e < 8; ++e) { o0[e] = tmpo[e]; o1[e] = tmpo[8+e]; }
                *(f16v8*)(qrow) = o0;
                *(f16v8*)(qrow + 8) = o1;
            }
        }
        if (g < NGRP) __syncthreads();
    }
}

// ---- products: I and I*I into 9-plane/b fp32 compact buffer ----------------
__global__ __launch_bounds__(256) void prod_k(float* __restrict__ Pf,
                                              const float* __restrict__ Refs) {
    int idx = blockIdx.x * 256 + threadIdx.x;
    int b = idx >> 18, pix = idx & (HW - 1);
    float I0 = Refs[((size_t)b * 3 + 0) * HW + pix];
    float I1 = Refs[((size_t)b * 3 + 1) * HW + pix];
    float I2 = Refs[((size_t)b * 3 + 2) * HW + pix];
    size_t base = (size_t)b * 9 * HW + pix;
    Pf[base + (size_t)0 * HW] = I0;
    Pf[base + (size_t)1 * HW] = I1;
    Pf[base + (size_t)2 * HW] = I2;
    Pf[base + (size_t)3 * HW] = I0 * I0;
    Pf[base + (size_t)4 * HW] = I0 * I1;
    Pf[base + (size_t)5 * HW] = I0 * I2;
    Pf[base + (size_t)6 * HW] = I1 * I1;
    Pf[base + (size_t)7 * HW] = I1 * I2;
    Pf[base + (size_t)8 * HW] = I2 * I2;
}

// ---- prep: boxed(I,II) fp32 -> Ainv (6 planes), mI (3 planes) --------------
__global__ __launch_bounds__(256) void prep_k(const float* __restrict__ Bf,
                                              float* __restrict__ Ainv, float* __restrict__ mI,
                                              const float* __restrict__ epsp) {
    int idx = blockIdx.x * 256 + threadIdx.x;
    int b = idx >> 18, pix = idx & (HW - 1);
    int x = pix & (WW - 1), y = pix >> 9;
    float nrm = nrminv(x, y);
    float eps = epsp[0];
    size_t base = (size_t)b * 9 * HW + pix;
    float m0 = Bf[base + (size_t)0 * HW] * nrm;
    float m1 = Bf[base + (size_t)1 * HW] * nrm;
    float m2 = Bf[base + (size_t)2 * HW] * nrm;
    float v00 = Bf[base + (size_t)3 * HW] * nrm - m0 * m0 + eps;
    float v01 = Bf[base + (size_t)4 * HW] * nrm - m0 * m1;
    float v02 = Bf[base + (size_t)5 * HW] * nrm - m0 * m2;
    float v11 = Bf[base + (size_t)6 * HW] * nrm - m1 * m1 + eps;
    float v12 = Bf[base + (size_t)7 * HW] * nrm - m1 * m2;
    float v22 = Bf[base + (size_t)8 * HW] * nrm - m2 * m2 + eps;
    float c00 = v11 * v22 - v12 * v12;
    float c01 = v02 * v12 - v01 * v22;
    float c02 = v01 * v12 - v02 * v11;
    float c11 = v00 * v22 - v02 * v02;
    float c12 = v01 * v02 - v00 * v12;
    float c22 = v00 * v11 - v01 * v01;
    float det = v00 * c00 + v01 * c01 + v02 * c02;
    float id = 1.0f / det;
    size_t ab = (size_t)b * 6 * HW + pix;
    Ainv[ab + (size_t)0 * HW] = c00 * id;
    Ainv[ab + (size_t)1 * HW] = c01 * id;
    Ainv[ab + (size_t)2 * HW] = c02 * id;
    Ainv[ab + (size_t)3 * HW] = c11 * id;
    Ainv[ab + (size_t)4 * HW] = c12 * id;
    Ainv[ab + (size_t)5 * HW] = c22 * id;
    size_t mb = (size_t)b * 3 * HW + pix;
    mI[mb]                  = m0;
    mI[mb + (size_t)HW]     = m1;
    mI[mb + (size_t)2 * HW] = m2;
}

// ---- fused: E=E0+q, Q=softmax(-E), p=W.Q, Ip (2 px/thread) -----------------
// mode 0: Q0 from E0 only; 1: mid; 2: last (fp32 Q -> out)
__global__ __launch_bounds__(256) void e_k(const f16* __restrict__ Q,
                                           f16* __restrict__ pout,
                                           const float* __restrict__ E0,
                                           const float* __restrict__ Refs,
                                           const float* __restrict__ Wf,
                                           float* __restrict__ out, int mode) {
    int idx = blockIdx.x * 256 + threadIdx.x;
    int b = idx >> 17;
    int pix = (idx & (HW / 2 - 1)) * 2;
    size_t base  = (size_t)b * NCH * HW + pix;
    size_t ebase = (size_t)b * LL * HW + pix;
    float2 Ic0 = *(const float2*)(Refs + ((size_t)b * 3 + 0) * HW + pix);
    float2 Ic1 = *(const float2*)(Refs + ((size_t)b * 3 + 1) * HW + pix);
    float2 Ic2 = *(const float2*)(Refs + ((size_t)b * 3 + 2) * HW + pix);
    float Ev0[LL], Ev1[LL];
    float m0 = -1e30f, m1 = -1e30f;
    #pragma unroll
    for (int l = 0; l < LL; ++l) {
        float2 e0 = *(const float2*)(E0 + ebase + (size_t)l * HW);
        float v0 = e0.x, v1 = e0.y;
        if (mode != 0) {
            f16v2 qv = *(const f16v2*)(Q + ebase + (size_t)l * HW);
            v0 += (float)qv.x; v1 += (float)qv.y;
        }
        Ev0[l] = -v0; Ev1[l] = -v1;
        m0 = fmaxf(m0, Ev0[l]); m1 = fmaxf(m1, Ev1[l]);
    }
    float s0 = 0.f, s1 = 0.f;
    #pragma unroll
    for (int l = 0; l < LL; ++l) {
        Ev0[l] = __expf(Ev0[l] - m0); s0 += Ev0[l];
        Ev1[l] = __expf(Ev1[l] - m1); s1 += Ev1[l];
    }
    float i0 = 1.0f / s0, i1 = 1.0f / s1;
    if (mode == 2) {
        #pragma unroll
        for (int l = 0; l < LL; ++l) {
            float2 o; o.x = Ev0[l] * i0; o.y = Ev1[l] * i1;
            *(float2*)(out + ebase + (size_t)l * HW) = o;
        }
    } else {
        #pragma unroll
        for (int l = 0; l < LL; ++l) { Ev0[l] *= i0; Ev1[l] *= i1; }
        #pragma unroll
        for (int l = 0; l < LL; ++l) {
            float p0 = 0.f, p1 = 0.f;
            #pragma unroll
            for (int m = 0; m < LL; ++m) {
                float w = Wf[l * LL + m];
                p0 += w * Ev0[m]; p1 += w * Ev1[m];
            }
            f16v2 o;
            o.x = (f16)p0; o.y = (f16)p1;
            *(f16v2*)(pout + base + (size_t)l * HW) = o;
            o.x = (f16)(p0 * Ic0.x); o.y = (f16)(p1 * Ic0.y);
            *(f16v2*)(pout + base + (size_t)(LL + 0*LL + l) * HW) = o;
            o.x = (f16)(p0 * Ic1.x); o.y = (f16)(p1 * Ic1.y);
            *(f16v2*)(pout + base + (size_t)(LL + 1*LL + l) * HW) = o;
            o.x = (f16)(p0 * Ic2.x); o.y = (f16)(p1 * Ic2.y);
            *(f16v2*)(pout + base + (size_t)(LL + 2*LL + l) * HW) = o;
        }
    }
}

// ---- host ------------------------------------------------------------------
extern "C" void kernel_launch(void* const* d_in, const int* in_sizes, int n_in,
                              void* d_out, int out_size, void* d_ws, size_t ws_size,
                              hipStream_t stream) {
    const float* E0   = (const float*)d_in[0];
    const float* Refs = (const float*)d_in[1];
    const float* Wmu  = (const float*)d_in[2];
    const float* epsp = (const float*)d_in[3];
    float* out = (float*)d_out;

    size_t Ub = (size_t)BB * NCH * HW * 2;   // 84 MB fp16
    size_t Ab = (size_t)BB * 6 * HW * 4;     // 12 MB fp32
    size_t Mb = (size_t)BB * 3 * HW * 4;     // 6 MB fp32
    char* ws = (char*)d_ws;
    f16*   U    = (f16*)ws;
    f16*   V    = (f16*)(ws + Ub);           // loop: holds b,a planes (solve out)
    float* Ainv = (float*)(ws + 2 * Ub);
    float* mI   = (float*)(ws + 2 * Ub + Ab);
    f16*   Qb   = (f16*)(ws + 2 * Ub + Ab + Mb);  // 21 fp16 q planes x BB
    float* Uf   = (float*)U;                 // init fp32 alias (9 planes/b)
    float* Vf   = (float*)V;

    int nblk = (BB * HW) / 256;
    // init: I, I*I -> 2D box (fp32) -> Ainv, mI
    prod_k<<<nblk, 256, 0, stream>>>(Uf, Refs);
    vboxf_k<<<dim3(HH / VSEG, BB * 9), 128, 0, stream>>>(Uf, Vf);
    hboxf_k<<<dim3(HH / 8, BB * 9), 256, 0, stream>>>(Vf, Uf);
    prep_k<<<nblk, 256, 0, stream>>>(Uf, Ainv, mI, epsp);
    // Q0 -> p, Ip into U (mode 0 reads no Q)
    e_k<<<(BB * HW / 2) / 256, 256, 0, stream>>>(Qb, U, E0, Refs, Wmu, out, 0);

    for (int t = 1; t <= 5; ++t) {
        fused_solve_k<<<dim3(NSTRIP, BB * LL), 512, 0, stream>>>(U, V, Ainv, mI);
        fused_q_k<<<dim3(NSTRIP, BB * LL), 512, 0, stream>>>(V, Refs, Qb);
        e_k<<<(BB * HW / 2) / 256, 256, 0, stream>>>(Qb, U, E0, Refs, Wmu, out,
                                                     t == 5 ? 2 : 1);
    }
}